// Round 10
// baseline (127.361 us; speedup 1.0000x reference)
//
#include <hip/hip_runtime.h>

#define B_SZ  2
#define N_PTS 16384
#define M_CTR 4096
#define C_FT  32
#define K_NB  32
#define NCH   35   // 3 + C_FT
#define CH_STRIDE (K_NB * M_CTR)   // 131072
#define CELLS 10
#define NCELL (CELLS * CELLS * CELLS)

// ---------------------------------------------------------------------------
// Exact single-rounded f32 ops, opaque to the compiler. v_fma_f32 ONLY where
// the numpy golden fuses (einsum cp accumulation). absmax==0.0 since R6 —
// DO NOT change the math.
// ---------------------------------------------------------------------------
__device__ __forceinline__ float fmul(float a, float b) {
    float r; asm("v_mul_f32 %0, %1, %2" : "=v"(r) : "v"(a), "v"(b)); return r;
}
__device__ __forceinline__ float fadd(float a, float b) {
    float r; asm("v_add_f32 %0, %1, %2" : "=v"(r) : "v"(a), "v"(b)); return r;
}
__device__ __forceinline__ float fsub(float a, float b) {
    float r; asm("v_sub_f32 %0, %1, %2" : "=v"(r) : "v"(a), "v"(b)); return r;
}
__device__ __forceinline__ float ffma(float a, float b, float c) {
    float r; asm("v_fma_f32 %0, %1, %2, %3" : "=v"(r) : "v"(a), "v"(b), "v"(c));
    return r;
}

__device__ __forceinline__ bool bq_valid(float x, float y, float z,
                                         float cx, float cy, float cz,
                                         float c2, float r2) {
    const float p2 = fadd(fadd(fmul(x, x), fmul(y, y)), fmul(z, z));
    const float cp = ffma(cz, z, ffma(cy, y, fmul(cx, x)));
    return fsub(fadd(c2, p2), fmul(2.0f, cp)) < r2;
}

__device__ __forceinline__ int cell_of(float x, float y, float z) {
    int ci = (int)(x * 10.0f); ci = ci < 0 ? 0 : (ci > 9 ? 9 : ci);
    int cj = (int)(y * 10.0f); cj = cj < 0 ? 0 : (cj > 9 ? 9 : cj);
    int ck = (int)(z * 10.0f); ck = ck < 0 ? 0 : (ck > 9 ? 9 : ck);
    return (ck * CELLS + cj) * CELLS + ci;   // x fastest
}

// ---------------------------------------------------------------------------
// Prep: ONE dispatch. Blocks 0..1: full per-batch binning (LDS hist -> LDS
// shuffle-scan -> LDS-cursor scatter) replacing memset+hist+scan+scatter.
// Blocks 2..513: transpose points+feats -> pf (B,N,36).
// Scatter order within a cell is racy-arbitrary: fine, bq's bitmap re-orders.
// ---------------------------------------------------------------------------
__global__ __launch_bounds__(256) void prep_kernel(
    const float* __restrict__ points,   // (B,3,N)
    const float* __restrict__ feats,    // (B,C,N)
    float4* __restrict__ binned,        // (B,N) {x,y,z,idx}
    int* __restrict__ starts,           // (B,1001)
    float* __restrict__ pf)             // (B,N,36)
{
    if (blockIdx.x < B_SZ) {
        const int b = blockIdx.x;
        const int t = threadIdx.x;
        const int lane = t & 63, wid = t >> 6;
        __shared__ int h[NCELL];
        __shared__ int cur[NCELL];
        __shared__ int wsum[4];
        for (int c = t; c < NCELL; c += 256) h[c] = 0;
        __syncthreads();

        const float* __restrict__ px = points + (b * 3 + 0) * N_PTS;
        const float* __restrict__ py = points + (b * 3 + 1) * N_PTS;
        const float* __restrict__ pz = points + (b * 3 + 2) * N_PTS;

#pragma unroll 4
        for (int i = 0; i < 64; ++i) {
            const int n = t + i * 256;
            atomicAdd(&h[cell_of(px[n], py[n], pz[n])], 1);
        }
        __syncthreads();

        // scan: 4 cells/thread (250 threads active), shuffle-scan of sums
        const int c0 = t * 4;
        int h0 = 0, h1 = 0, h2 = 0, h3 = 0;
        if (c0 < NCELL) { h0 = h[c0]; h1 = h[c0+1]; h2 = h[c0+2]; h3 = h[c0+3]; }
        const int s = h0 + h1 + h2 + h3;
        int incl = s;
        for (int off = 1; off < 64; off <<= 1) {
            const int u = __shfl_up(incl, off);
            if (lane >= off) incl += u;
        }
        if (lane == 63) wsum[wid] = incl;
        __syncthreads();
        const int woff = (wid > 0 ? wsum[0] : 0) + (wid > 1 ? wsum[1] : 0)
                       + (wid > 2 ? wsum[2] : 0);
        if (c0 < NCELL) {
            int e = incl - s + woff;
            int* st = starts + b * (NCELL + 1);
            st[c0] = e;     cur[c0] = e;     e += h0;
            st[c0+1] = e;   cur[c0+1] = e;   e += h1;
            st[c0+2] = e;   cur[c0+2] = e;   e += h2;
            st[c0+3] = e;   cur[c0+3] = e;   e += h3;
            if (c0 + 4 == NCELL) st[NCELL] = e;
        }
        __syncthreads();

        // scatter (re-read coords; L1/L2 hot)
#pragma unroll 4
        for (int i = 0; i < 64; ++i) {
            const int n = t + i * 256;
            const float x = px[n], y = py[n], z = pz[n];
            const int pos = atomicAdd(&cur[cell_of(x, y, z)], 1);
            binned[b * N_PTS + pos] = make_float4(x, y, z, __int_as_float(n));
        }
    } else {
        __shared__ float tile[64][37];
        const int bid = blockIdx.x - B_SZ;
        const int t  = threadIdx.x;
        const int b  = bid >> 8;
        const int n0 = (bid & 255) * 64;
        for (int i = t; i < NCH * 64; i += 256) {
            const int r = i >> 6;
            const int c = i & 63;
            float v;
            if (r < 3) v = points[(b * 3 + r) * N_PTS + n0 + c];
            else       v = feats[(b * C_FT + (r - 3)) * N_PTS + n0 + c];
            tile[c][r] = v;
        }
        if (t < 64) tile[t][35] = 0.0f;
        __syncthreads();
        float* __restrict__ dst = pf + ((size_t)b * N_PTS + n0) * 36;
        for (int o = t; o < 64 * 36; o += 256) {
            const int c = o / 36;
            const int r = o - c * 36;
            dst[o] = tile[c][r];
        }
    }
}

// ---------------------------------------------------------------------------
// Ball query, binned. One wave per center; 27-cell neighborhood (~440
// candidates). Per-wave LDS bitmap over N restores exact index order.
// ---------------------------------------------------------------------------
__global__ __launch_bounds__(256) void ball_query_kernel(
    const float4* __restrict__ binned,   // (B,N) {x,y,z,idx}
    const float* __restrict__ centers,   // (B,3,M)
    const int* __restrict__ starts,      // (B,1001)
    int* __restrict__ idx_out)           // (B,K,M)
{
    const int lane = threadIdx.x & 63;
    const int wid  = threadIdx.x >> 6;
    const int cid  = blockIdx.x * 4 + wid;
    const int b = cid >> 12;
    const int m = cid & (M_CTR - 1);

    const float r2 = (float)(0.1 * 0.1);

    const float cx = centers[(b * 3 + 0) * M_CTR + m];
    const float cy = centers[(b * 3 + 1) * M_CTR + m];
    const float cz = centers[(b * 3 + 2) * M_CTR + m];
    const float c2 = fadd(fadd(fmul(cx, cx), fmul(cy, cy)), fmul(cz, cz));

    __shared__ unsigned bitmap[4][N_PTS / 32];   // 2 KB per wave
    unsigned* bm = bitmap[wid];
#pragma unroll
    for (int j = 0; j < 8; ++j) bm[lane * 8 + j] = 0u;

    int ci = (int)(cx * 10.0f); ci = ci < 0 ? 0 : (ci > 9 ? 9 : ci);
    int cj = (int)(cy * 10.0f); cj = cj < 0 ? 0 : (cj > 9 ? 9 : cj);
    int ck = (int)(cz * 10.0f); ck = ck < 0 ? 0 : (ck > 9 ? 9 : ck);
    const int i0 = ci > 0 ? ci - 1 : 0;
    const int i1 = ci < 9 ? ci + 1 : 9;
    const int* st = starts + b * (NCELL + 1);
    const float4* __restrict__ bp = binned + b * N_PTS;

    for (int d = 0; d < 9; ++d) {
        const int jj = cj + (d % 3) - 1;
        const int kk = ck + (d / 3) - 1;
        if (jj < 0 || jj > 9 || kk < 0 || kk > 9) continue;
        const int base = (kk * CELLS + jj) * CELLS;
        const int lo = st[base + i0];
        const int hi = st[base + i1 + 1];
        for (int s0 = lo; s0 < hi; s0 += 64) {
            const int t = s0 + lane;
            if (t < hi) {
                const float4 p = bp[t];
                if (bq_valid(p.x, p.y, p.z, cx, cy, cz, c2, r2)) {
                    const int n = __float_as_int(p.w);
                    atomicOr((int*)&bm[n >> 5], 1 << (n & 31));
                }
            }
        }
    }

    unsigned w[8];
    int cnt = 0;
#pragma unroll
    for (int j = 0; j < 8; ++j) { w[j] = bm[lane * 8 + j]; cnt += __popc(w[j]); }

    int incl = cnt;
    for (int off = 1; off < 64; off <<= 1) {
        const int v = __shfl_up(incl, off);
        if (lane >= off) incl += v;
    }
    const int total = __shfl(incl, 63);
    int slot = incl - cnt;

    int firstbit = 0x7fffffff;
#pragma unroll
    for (int j = 0; j < 8; ++j) {
        if (w[j] && firstbit == 0x7fffffff)
            firstbit = lane * 256 + j * 32 + (__ffs(w[j]) - 1);
    }
    for (int off = 32; off > 0; off >>= 1)
        firstbit = min(firstbit, __shfl_xor(firstbit, off));
    const int first_idx = (total == 0) ? 0 : firstbit;

    int* __restrict__ dst = idx_out + (b * K_NB) * M_CTR + m;
#pragma unroll
    for (int j = 0; j < 8; ++j) {
        unsigned x = w[j];
        while (x && slot < K_NB) {
            const int bit = __ffs(x) - 1;
            dst[slot * M_CTR] = lane * 256 + j * 32 + bit;
            x &= x - 1;
            ++slot;
        }
    }
    if (lane >= total && lane < K_NB) dst[lane * M_CTR] = first_idx;
}

// ---------------------------------------------------------------------------
// Gather: 4 consecutive-m elements per thread. dwordx4 plane stores
// (1 KB/wave), int4 idx loads, 4-record MLP, register transpose per group.
// ---------------------------------------------------------------------------
__global__ __launch_bounds__(256) void gather_kernel(
    const float* __restrict__ pf,       // (B,N,36)
    const float* __restrict__ centers,  // (B,3,M)
    const int* __restrict__ idx,        // (B,K,M)
    float* __restrict__ out)            // (B,35,K,M)
{
    const int t = blockIdx.x * 256 + threadIdx.x;   // 0..65535
    const int m = (t & (M_CTR / 4 - 1)) * 4;
    const int k = (t >> 10) & (K_NB - 1);
    const int b = t >> 15;

    const int4 nn = *(const int4*)&idx[(b * K_NB + k) * M_CTR + m];
    const float4* __restrict__ r0 = (const float4*)(pf + ((size_t)b * N_PTS + nn.x) * 36);
    const float4* __restrict__ r1 = (const float4*)(pf + ((size_t)b * N_PTS + nn.y) * 36);
    const float4* __restrict__ r2 = (const float4*)(pf + ((size_t)b * N_PTS + nn.z) * 36);
    const float4* __restrict__ r3 = (const float4*)(pf + ((size_t)b * N_PTS + nn.w) * 36);

    const float4 cx = *(const float4*)&centers[(b * 3 + 0) * M_CTR + m];
    const float4 cy = *(const float4*)&centers[(b * 3 + 1) * M_CTR + m];
    const float4 cz = *(const float4*)&centers[(b * 3 + 2) * M_CTR + m];

    float* __restrict__ o = out + ((size_t)b * NCH * K_NB + k) * M_CTR + m;

#pragma unroll
    for (int g = 0; g < 9; ++g) {
        float4 a = r0[g], e = r1[g], f = r2[g], h = r3[g];
        if (g == 0) {   // channels 0..2 = coords: single f32 subtract (exact)
            a.x -= cx.x; a.y -= cy.x; a.z -= cz.x;
            e.x -= cx.y; e.y -= cy.y; e.z -= cz.y;
            f.x -= cx.z; f.y -= cy.z; f.z -= cz.z;
            h.x -= cx.w; h.y -= cy.w; h.z -= cz.w;
        }
        *(float4*)&o[(size_t)(4 * g + 0) * CH_STRIDE] = make_float4(a.x, e.x, f.x, h.x);
        *(float4*)&o[(size_t)(4 * g + 1) * CH_STRIDE] = make_float4(a.y, e.y, f.y, h.y);
        *(float4*)&o[(size_t)(4 * g + 2) * CH_STRIDE] = make_float4(a.z, e.z, f.z, h.z);
        if (g < 8)
            *(float4*)&o[(size_t)(4 * g + 3) * CH_STRIDE] = make_float4(a.w, e.w, f.w, h.w);
    }
}

extern "C" void kernel_launch(void* const* d_in, const int* in_sizes, int n_in,
                              void* d_out, int out_size, void* d_ws, size_t ws_size,
                              hipStream_t stream) {
    const float* points  = (const float*)d_in[0];
    const float* centers = (const float*)d_in[1];
    const float* feats   = (const float*)d_in[2];
    float* out = (float*)d_out;

    char* ws = (char*)d_ws;
    int*    idx    = (int*)ws;                               // 1 MiB
    float*  pf     = (float*)(ws + (1u << 20));              // 4.5 MiB
    int*    starts = (int*)(ws + 5732 * 1024);               // 8 KB
    float4* binned = (float4*)(ws + 5764 * 1024);            // 512 KB

    prep_kernel<<<B_SZ + B_SZ * (N_PTS / 64), 256, 0, stream>>>(
        points, feats, binned, starts, pf);
    ball_query_kernel<<<(B_SZ * M_CTR) / 4, 256, 0, stream>>>(
        binned, centers, starts, idx);
    gather_kernel<<<(B_SZ * K_NB * M_CTR / 4) / 256, 256, 0, stream>>>(
        pf, centers, idx, out);
}

// Round 11
// 112.717 us; speedup vs baseline: 1.1299x; 1.1299x over previous
//
#include <hip/hip_runtime.h>

#define B_SZ  2
#define N_PTS 16384
#define M_CTR 4096
#define C_FT  32
#define K_NB  32
#define NCH   35   // 3 + C_FT
#define CH_STRIDE (K_NB * M_CTR)   // 131072
#define CELLS 10
#define NCELL (CELLS * CELLS * CELLS)

// ---------------------------------------------------------------------------
// Exact single-rounded f32 ops, opaque to the compiler. v_fma_f32 ONLY where
// the numpy golden fuses (einsum cp accumulation). absmax==0.0 since R6 —
// DO NOT change the math.
// ---------------------------------------------------------------------------
__device__ __forceinline__ float fmul(float a, float b) {
    float r; asm("v_mul_f32 %0, %1, %2" : "=v"(r) : "v"(a), "v"(b)); return r;
}
__device__ __forceinline__ float fadd(float a, float b) {
    float r; asm("v_add_f32 %0, %1, %2" : "=v"(r) : "v"(a), "v"(b)); return r;
}
__device__ __forceinline__ float fsub(float a, float b) {
    float r; asm("v_sub_f32 %0, %1, %2" : "=v"(r) : "v"(a), "v"(b)); return r;
}
__device__ __forceinline__ float ffma(float a, float b, float c) {
    float r; asm("v_fma_f32 %0, %1, %2, %3" : "=v"(r) : "v"(a), "v"(b), "v"(c));
    return r;
}

__device__ __forceinline__ bool bq_valid(float x, float y, float z,
                                         float cx, float cy, float cz,
                                         float c2, float r2) {
    const float p2 = fadd(fadd(fmul(x, x), fmul(y, y)), fmul(z, z));
    const float cp = ffma(cz, z, ffma(cy, y, fmul(cx, x)));
    return fsub(fadd(c2, p2), fmul(2.0f, cp)) < r2;
}

__device__ __forceinline__ int cell_of(float x, float y, float z) {
    int ci = (int)(x * 10.0f); ci = ci < 0 ? 0 : (ci > 9 ? 9 : ci);
    int cj = (int)(y * 10.0f); cj = cj < 0 ? 0 : (cj > 9 ? 9 : cj);
    int ck = (int)(z * 10.0f); ck = ck < 0 ? 0 : (ck > 9 ? 9 : ck);
    return (ck * CELLS + cj) * CELLS + ci;   // x fastest
}

// --- hist (hist[] zeroed by hipMemsetAsync). Parallel: 128 blocks. ---------
// R10 lesson: single-block-per-batch binning serializes ~400KB of loads onto
// 2 CUs (+10us critical path). Keep binning parallel.
__global__ __launch_bounds__(256) void hist_kernel(
    const float* __restrict__ points, int* __restrict__ hist) {
    const int t = blockIdx.x * 256 + threadIdx.x;
    const int b = t >> 14, n = t & (N_PTS - 1);
    const float x = points[(b * 3 + 0) * N_PTS + n];
    const float y = points[(b * 3 + 1) * N_PTS + n];
    const float z = points[(b * 3 + 2) * N_PTS + n];
    atomicAdd(&hist[b * NCELL + cell_of(x, y, z)], 1);
}

// --- scan: one block per batch, 2 barriers (shuffle scan) ------------------
__global__ __launch_bounds__(1024) void scan_kernel(
    const int* __restrict__ hist, int* __restrict__ starts,
    int* __restrict__ cursor) {
    const int b = blockIdx.x;
    const int t = threadIdx.x;
    const int lane = t & 63, wid = t >> 6;
    __shared__ int wsum[16];
    const int v = (t < NCELL) ? hist[b * NCELL + t] : 0;
    int incl = v;
    for (int off = 1; off < 64; off <<= 1) {
        const int u = __shfl_up(incl, off);
        if (lane >= off) incl += u;
    }
    if (lane == 63) wsum[wid] = incl;
    __syncthreads();
    if (wid == 0 && lane < 16) {
        const int s = wsum[lane];
        int in2 = s;
        for (int off = 1; off < 16; off <<= 1) {
            const int u = __shfl_up(in2, off);
            if (lane >= off) in2 += u;
        }
        wsum[lane] = in2 - s;
    }
    __syncthreads();
    if (t < NCELL) {
        const int excl = incl - v + wsum[wid];
        starts[b * (NCELL + 1) + t] = excl;
        cursor[b * NCELL + t] = excl;
        if (t == NCELL - 1) starts[b * (NCELL + 1) + NCELL] = excl + v;
    }
}

// --- fused scatter (blocks 0..127) + transpose (blocks 128..639) -----------
__global__ __launch_bounds__(256) void scatter_transpose_kernel(
    const float* __restrict__ points, const float* __restrict__ feats,
    int* __restrict__ cursor, float4* __restrict__ binned,
    float* __restrict__ pf) {
    if (blockIdx.x < 128) {
        const int t = blockIdx.x * 256 + threadIdx.x;
        const int b = t >> 14, n = t & (N_PTS - 1);
        const float x = points[(b * 3 + 0) * N_PTS + n];
        const float y = points[(b * 3 + 1) * N_PTS + n];
        const float z = points[(b * 3 + 2) * N_PTS + n];
        const int pos = atomicAdd(&cursor[b * NCELL + cell_of(x, y, z)], 1);
        binned[b * N_PTS + pos] = make_float4(x, y, z, __int_as_float(n));
    } else {
        __shared__ float tile[64][37];
        const int bid = blockIdx.x - 128;
        const int t  = threadIdx.x;
        const int b  = bid >> 8;
        const int n0 = (bid & 255) * 64;
        for (int i = t; i < NCH * 64; i += 256) {
            const int r = i >> 6;
            const int c = i & 63;
            float v;
            if (r < 3) v = points[(b * 3 + r) * N_PTS + n0 + c];
            else       v = feats[(b * C_FT + (r - 3)) * N_PTS + n0 + c];
            tile[c][r] = v;
        }
        if (t < 64) tile[t][35] = 0.0f;
        __syncthreads();
        float* __restrict__ dst = pf + ((size_t)b * N_PTS + n0) * 36;
        for (int o = t; o < 64 * 36; o += 256) {
            const int c = o / 36;
            const int r = o - c * 36;
            dst[o] = tile[c][r];
        }
    }
}

// ---------------------------------------------------------------------------
// Ball query, binned. One wave per center; 27-cell neighborhood (~440
// candidates). Per-wave LDS bitmap over N restores exact index order.
// ---------------------------------------------------------------------------
__global__ __launch_bounds__(256) void ball_query_kernel(
    const float4* __restrict__ binned,   // (B,N) {x,y,z,idx}
    const float* __restrict__ centers,   // (B,3,M)
    const int* __restrict__ starts,      // (B,1001)
    int* __restrict__ idx_out)           // (B,K,M)
{
    const int lane = threadIdx.x & 63;
    const int wid  = threadIdx.x >> 6;
    const int cid  = blockIdx.x * 4 + wid;
    const int b = cid >> 12;
    const int m = cid & (M_CTR - 1);

    const float r2 = (float)(0.1 * 0.1);

    const float cx = centers[(b * 3 + 0) * M_CTR + m];
    const float cy = centers[(b * 3 + 1) * M_CTR + m];
    const float cz = centers[(b * 3 + 2) * M_CTR + m];
    const float c2 = fadd(fadd(fmul(cx, cx), fmul(cy, cy)), fmul(cz, cz));

    __shared__ unsigned bitmap[4][N_PTS / 32];   // 2 KB per wave
    unsigned* bm = bitmap[wid];
#pragma unroll
    for (int j = 0; j < 8; ++j) bm[lane * 8 + j] = 0u;

    int ci = (int)(cx * 10.0f); ci = ci < 0 ? 0 : (ci > 9 ? 9 : ci);
    int cj = (int)(cy * 10.0f); cj = cj < 0 ? 0 : (cj > 9 ? 9 : cj);
    int ck = (int)(cz * 10.0f); ck = ck < 0 ? 0 : (ck > 9 ? 9 : ck);
    const int i0 = ci > 0 ? ci - 1 : 0;
    const int i1 = ci < 9 ? ci + 1 : 9;
    const int* st = starts + b * (NCELL + 1);
    const float4* __restrict__ bp = binned + b * N_PTS;

    for (int d = 0; d < 9; ++d) {
        const int jj = cj + (d % 3) - 1;
        const int kk = ck + (d / 3) - 1;
        if (jj < 0 || jj > 9 || kk < 0 || kk > 9) continue;
        const int base = (kk * CELLS + jj) * CELLS;
        const int lo = st[base + i0];
        const int hi = st[base + i1 + 1];
        for (int s0 = lo; s0 < hi; s0 += 64) {
            const int t = s0 + lane;
            if (t < hi) {
                const float4 p = bp[t];
                if (bq_valid(p.x, p.y, p.z, cx, cy, cz, c2, r2)) {
                    const int n = __float_as_int(p.w);
                    atomicOr((int*)&bm[n >> 5], 1 << (n & 31));
                }
            }
        }
    }

    unsigned w[8];
    int cnt = 0;
#pragma unroll
    for (int j = 0; j < 8; ++j) { w[j] = bm[lane * 8 + j]; cnt += __popc(w[j]); }

    int incl = cnt;
    for (int off = 1; off < 64; off <<= 1) {
        const int v = __shfl_up(incl, off);
        if (lane >= off) incl += v;
    }
    const int total = __shfl(incl, 63);
    int slot = incl - cnt;

    int firstbit = 0x7fffffff;
#pragma unroll
    for (int j = 0; j < 8; ++j) {
        if (w[j] && firstbit == 0x7fffffff)
            firstbit = lane * 256 + j * 32 + (__ffs(w[j]) - 1);
    }
    for (int off = 32; off > 0; off >>= 1)
        firstbit = min(firstbit, __shfl_xor(firstbit, off));
    const int first_idx = (total == 0) ? 0 : firstbit;

    int* __restrict__ dst = idx_out + (b * K_NB) * M_CTR + m;
#pragma unroll
    for (int j = 0; j < 8; ++j) {
        unsigned x = w[j];
        while (x && slot < K_NB) {
            const int bit = __ffs(x) - 1;
            dst[slot * M_CTR] = lane * 256 + j * 32 + bit;
            x &= x - 1;
            ++slot;
        }
    }
    if (lane >= total && lane < K_NB) dst[lane * M_CTR] = first_idx;
}

// ---------------------------------------------------------------------------
// Gather, pass-split: thread = (g, b, k, m/4), g slowest (wave-uniform).
// Per thread: 1 coalesced int4 idx load, 4 random float4 record loads
// (16B of the record's channel-group g), 4 (3 for g=8) float4 plane stores
// (1KB/wave, coalesced). VGPR ~40 — R10's 36-hoisted-load spill avoided;
// MLP from thread count, not unroll.
// ---------------------------------------------------------------------------
__global__ __launch_bounds__(256) void gather_kernel(
    const float* __restrict__ pf,       // (B,N,36)
    const float* __restrict__ centers,  // (B,3,M)
    const int* __restrict__ idx,        // (B,K,M)
    float* __restrict__ out)            // (B,35,K,M)
{
    const int t = blockIdx.x * 256 + threadIdx.x;   // 0..589823
    const int g = t >> 16;                           // 0..8, wave-uniform
    const int rem = t & 65535;
    const int m = (rem & (M_CTR / 4 - 1)) * 4;
    const int k = (rem >> 10) & (K_NB - 1);
    const int b = rem >> 15;

    const int4 nn = *(const int4*)&idx[(b * K_NB + k) * M_CTR + m];
    const size_t pb = (size_t)b * N_PTS;
    float4 a = *(const float4*)(pf + (pb + nn.x) * 36 + g * 4);
    float4 e = *(const float4*)(pf + (pb + nn.y) * 36 + g * 4);
    float4 f = *(const float4*)(pf + (pb + nn.z) * 36 + g * 4);
    float4 h = *(const float4*)(pf + (pb + nn.w) * 36 + g * 4);

    if (g == 0) {   // channels 0..2 = coords: single f32 subtract (exact)
        const float4 cx = *(const float4*)&centers[(b * 3 + 0) * M_CTR + m];
        const float4 cy = *(const float4*)&centers[(b * 3 + 1) * M_CTR + m];
        const float4 cz = *(const float4*)&centers[(b * 3 + 2) * M_CTR + m];
        a.x -= cx.x; a.y -= cy.x; a.z -= cz.x;
        e.x -= cx.y; e.y -= cy.y; e.z -= cz.y;
        f.x -= cx.z; f.y -= cy.z; f.z -= cz.z;
        h.x -= cx.w; h.y -= cy.w; h.z -= cz.w;
    }

    float* __restrict__ o = out + ((size_t)b * NCH * K_NB + k) * M_CTR + m
                          + (size_t)(4 * g) * CH_STRIDE;
    *(float4*)&o[0]             = make_float4(a.x, e.x, f.x, h.x);
    *(float4*)&o[CH_STRIDE]     = make_float4(a.y, e.y, f.y, h.y);
    *(float4*)&o[2 * CH_STRIDE] = make_float4(a.z, e.z, f.z, h.z);
    if (g < 8)
        *(float4*)&o[3 * (size_t)CH_STRIDE] = make_float4(a.w, e.w, f.w, h.w);
}

extern "C" void kernel_launch(void* const* d_in, const int* in_sizes, int n_in,
                              void* d_out, int out_size, void* d_ws, size_t ws_size,
                              hipStream_t stream) {
    const float* points  = (const float*)d_in[0];
    const float* centers = (const float*)d_in[1];
    const float* feats   = (const float*)d_in[2];
    float* out = (float*)d_out;

    char* ws = (char*)d_ws;
    int*    idx    = (int*)ws;                               // 1 MiB
    float*  pf     = (float*)(ws + (1u << 20));              // 4.5 MiB
    int*    hist   = (int*)(ws + 5700 * 1024);               // 8 KB
    int*    cursor = (int*)(ws + 5716 * 1024);               // 8 KB
    int*    starts = (int*)(ws + 5732 * 1024);               // 8 KB
    float4* binned = (float4*)(ws + 5764 * 1024);            // 512 KB

    hipMemsetAsync(hist, 0, B_SZ * NCELL * sizeof(int), stream);
    hist_kernel<<<(B_SZ * N_PTS) / 256, 256, 0, stream>>>(points, hist);
    scan_kernel<<<B_SZ, 1024, 0, stream>>>(hist, starts, cursor);
    scatter_transpose_kernel<<<128 + B_SZ * (N_PTS / 64), 256, 0, stream>>>(
        points, feats, cursor, binned, pf);
    ball_query_kernel<<<(B_SZ * M_CTR) / 4, 256, 0, stream>>>(
        binned, centers, starts, idx);
    // 9 passes x (B*K*M/4) threads = 589,824 -> 2304 blocks
    gather_kernel<<<(9 * B_SZ * K_NB * (M_CTR / 4)) / 256, 256, 0, stream>>>(
        pf, centers, idx, out);
}

// Round 12
// 103.864 us; speedup vs baseline: 1.2262x; 1.0852x over previous
//
#include <hip/hip_runtime.h>

#define B_SZ  2
#define N_PTS 16384
#define M_CTR 4096
#define C_FT  32
#define K_NB  32
#define NCH   35   // 3 + C_FT
#define CH_STRIDE (K_NB * M_CTR)   // 131072
#define CELLS 10
#define NCELL (CELLS * CELLS * CELLS)

// ---------------------------------------------------------------------------
// Exact single-rounded f32 ops, opaque to the compiler. v_fma_f32 ONLY where
// the numpy golden fuses (einsum cp accumulation). absmax==0.0 since R6 —
// DO NOT change the math.
// ---------------------------------------------------------------------------
__device__ __forceinline__ float fmul(float a, float b) {
    float r; asm("v_mul_f32 %0, %1, %2" : "=v"(r) : "v"(a), "v"(b)); return r;
}
__device__ __forceinline__ float fadd(float a, float b) {
    float r; asm("v_add_f32 %0, %1, %2" : "=v"(r) : "v"(a), "v"(b)); return r;
}
__device__ __forceinline__ float fsub(float a, float b) {
    float r; asm("v_sub_f32 %0, %1, %2" : "=v"(r) : "v"(a), "v"(b)); return r;
}
__device__ __forceinline__ float ffma(float a, float b, float c) {
    float r; asm("v_fma_f32 %0, %1, %2, %3" : "=v"(r) : "v"(a), "v"(b), "v"(c));
    return r;
}

__device__ __forceinline__ bool bq_valid(float x, float y, float z,
                                         float cx, float cy, float cz,
                                         float c2, float r2) {
    const float p2 = fadd(fadd(fmul(x, x), fmul(y, y)), fmul(z, z));
    const float cp = ffma(cz, z, ffma(cy, y, fmul(cx, x)));
    return fsub(fadd(c2, p2), fmul(2.0f, cp)) < r2;
}

__device__ __forceinline__ int cell_of(float x, float y, float z) {
    int ci = (int)(x * 10.0f); ci = ci < 0 ? 0 : (ci > 9 ? 9 : ci);
    int cj = (int)(y * 10.0f); cj = cj < 0 ? 0 : (cj > 9 ? 9 : cj);
    int ck = (int)(z * 10.0f); ck = ck < 0 ? 0 : (ck > 9 ? 9 : ck);
    return (ck * CELLS + cj) * CELLS + ci;   // x fastest
}

// ---------------------------------------------------------------------------
// Prep, ONE dispatch @1024 threads:
//   blocks 0..1      : per-batch LDS hist (16 pts/thread) -> in-block
//                      shuffle-scan -> starts/cursor. Replaces
//                      memset+hist+scan (2 dispatches + gaps + global hist
//                      round-trip).
//   blocks 2..513    : transpose points+feats -> pf (B,N,36).
// The 512 transpose blocks keep the machine busy while 2 blocks bin —
// avoids R10's serialization (scatter traffic stays OUT of these blocks).
// ---------------------------------------------------------------------------
__global__ __launch_bounds__(1024) void prep_kernel(
    const float* __restrict__ points,   // (B,3,N)
    const float* __restrict__ feats,    // (B,C,N)
    int* __restrict__ starts,           // (B,1001)
    int* __restrict__ cursor,           // (B,1000)
    float* __restrict__ pf)             // (B,N,36)
{
    if (blockIdx.x < B_SZ) {
        const int b = blockIdx.x;
        const int t = threadIdx.x;      // 0..1023
        const int lane = t & 63, wid = t >> 6;
        __shared__ int h[NCELL];
        __shared__ int wsum[16];
        for (int c = t; c < NCELL; c += 1024) h[c] = 0;
        __syncthreads();

        const float* __restrict__ px = points + (b * 3 + 0) * N_PTS;
        const float* __restrict__ py = points + (b * 3 + 1) * N_PTS;
        const float* __restrict__ pz = points + (b * 3 + 2) * N_PTS;
#pragma unroll
        for (int i = 0; i < 16; ++i) {
            const int n = t + i * 1024;
            atomicAdd(&h[cell_of(px[n], py[n], pz[n])], 1);
        }
        __syncthreads();

        const int v = (t < NCELL) ? h[t] : 0;
        int incl = v;
        for (int off = 1; off < 64; off <<= 1) {
            const int u = __shfl_up(incl, off);
            if (lane >= off) incl += u;
        }
        if (lane == 63) wsum[wid] = incl;
        __syncthreads();
        if (wid == 0 && lane < 16) {
            const int s = wsum[lane];
            int in2 = s;
            for (int off = 1; off < 16; off <<= 1) {
                const int u = __shfl_up(in2, off);
                if (lane >= off) in2 += u;
            }
            wsum[lane] = in2 - s;       // exclusive wave offset
        }
        __syncthreads();
        if (t < NCELL) {
            const int excl = incl - v + wsum[wid];
            starts[b * (NCELL + 1) + t] = excl;
            cursor[b * NCELL + t] = excl;
            if (t == NCELL - 1) starts[b * (NCELL + 1) + NCELL] = excl + v;
        }
    } else {
        __shared__ float tile[64][37];
        const int bid = blockIdx.x - B_SZ;
        const int t  = threadIdx.x;
        const int b  = bid >> 8;
        const int n0 = (bid & 255) * 64;
        for (int i = t; i < NCH * 64; i += 1024) {
            const int r = i >> 6;
            const int c = i & 63;
            float v;
            if (r < 3) v = points[(b * 3 + r) * N_PTS + n0 + c];
            else       v = feats[(b * C_FT + (r - 3)) * N_PTS + n0 + c];
            tile[c][r] = v;
        }
        if (t < 64) tile[t][35] = 0.0f;
        __syncthreads();
        float* __restrict__ dst = pf + ((size_t)b * N_PTS + n0) * 36;
        for (int o = t; o < 64 * 36; o += 1024) {
            const int c = o / 36;
            const int r = o - c * 36;
            dst[o] = tile[c][r];
        }
    }
}

// --- scatter: parallel, 128 blocks (R10 lesson: keep off the 2 bin CUs) ----
__global__ __launch_bounds__(256) void scatter_kernel(
    const float* __restrict__ points, int* __restrict__ cursor,
    float4* __restrict__ binned) {
    const int t = blockIdx.x * 256 + threadIdx.x;
    const int b = t >> 14, n = t & (N_PTS - 1);
    const float x = points[(b * 3 + 0) * N_PTS + n];
    const float y = points[(b * 3 + 1) * N_PTS + n];
    const float z = points[(b * 3 + 2) * N_PTS + n];
    const int pos = atomicAdd(&cursor[b * NCELL + cell_of(x, y, z)], 1);
    binned[b * N_PTS + pos] = make_float4(x, y, z, __int_as_float(n));
}

// ---------------------------------------------------------------------------
// Ball query, binned. One wave per center; 27-cell neighborhood (~440
// candidates). Per-wave LDS bitmap over N restores exact index order.
// ---------------------------------------------------------------------------
__global__ __launch_bounds__(256) void ball_query_kernel(
    const float4* __restrict__ binned,   // (B,N) {x,y,z,idx}
    const float* __restrict__ centers,   // (B,3,M)
    const int* __restrict__ starts,      // (B,1001)
    int* __restrict__ idx_out)           // (B,K,M)
{
    const int lane = threadIdx.x & 63;
    const int wid  = threadIdx.x >> 6;
    const int cid  = blockIdx.x * 4 + wid;
    const int b = cid >> 12;
    const int m = cid & (M_CTR - 1);

    const float r2 = (float)(0.1 * 0.1);

    const float cx = centers[(b * 3 + 0) * M_CTR + m];
    const float cy = centers[(b * 3 + 1) * M_CTR + m];
    const float cz = centers[(b * 3 + 2) * M_CTR + m];
    const float c2 = fadd(fadd(fmul(cx, cx), fmul(cy, cy)), fmul(cz, cz));

    __shared__ unsigned bitmap[4][N_PTS / 32];   // 2 KB per wave
    unsigned* bm = bitmap[wid];
#pragma unroll
    for (int j = 0; j < 8; ++j) bm[lane * 8 + j] = 0u;

    int ci = (int)(cx * 10.0f); ci = ci < 0 ? 0 : (ci > 9 ? 9 : ci);
    int cj = (int)(cy * 10.0f); cj = cj < 0 ? 0 : (cj > 9 ? 9 : cj);
    int ck = (int)(cz * 10.0f); ck = ck < 0 ? 0 : (ck > 9 ? 9 : ck);
    const int i0 = ci > 0 ? ci - 1 : 0;
    const int i1 = ci < 9 ? ci + 1 : 9;
    const int* st = starts + b * (NCELL + 1);
    const float4* __restrict__ bp = binned + b * N_PTS;

    for (int d = 0; d < 9; ++d) {
        const int jj = cj + (d % 3) - 1;
        const int kk = ck + (d / 3) - 1;
        if (jj < 0 || jj > 9 || kk < 0 || kk > 9) continue;
        const int base = (kk * CELLS + jj) * CELLS;
        const int lo = st[base + i0];
        const int hi = st[base + i1 + 1];
        for (int s0 = lo; s0 < hi; s0 += 64) {
            const int t = s0 + lane;
            if (t < hi) {
                const float4 p = bp[t];
                if (bq_valid(p.x, p.y, p.z, cx, cy, cz, c2, r2)) {
                    const int n = __float_as_int(p.w);
                    atomicOr((int*)&bm[n >> 5], 1 << (n & 31));
                }
            }
        }
    }

    unsigned w[8];
    int cnt = 0;
#pragma unroll
    for (int j = 0; j < 8; ++j) { w[j] = bm[lane * 8 + j]; cnt += __popc(w[j]); }

    int incl = cnt;
    for (int off = 1; off < 64; off <<= 1) {
        const int v = __shfl_up(incl, off);
        if (lane >= off) incl += v;
    }
    const int total = __shfl(incl, 63);
    int slot = incl - cnt;

    int firstbit = 0x7fffffff;
#pragma unroll
    for (int j = 0; j < 8; ++j) {
        if (w[j] && firstbit == 0x7fffffff)
            firstbit = lane * 256 + j * 32 + (__ffs(w[j]) - 1);
    }
    for (int off = 32; off > 0; off >>= 1)
        firstbit = min(firstbit, __shfl_xor(firstbit, off));
    const int first_idx = (total == 0) ? 0 : firstbit;

    int* __restrict__ dst = idx_out + (b * K_NB) * M_CTR + m;
#pragma unroll
    for (int j = 0; j < 8; ++j) {
        unsigned x = w[j];
        while (x && slot < K_NB) {
            const int bit = __ffs(x) - 1;
            dst[slot * M_CTR] = lane * 256 + j * 32 + bit;
            x &= x - 1;
            ++slot;
        }
    }
    if (lane >= total && lane < K_NB) dst[lane * M_CTR] = first_idx;
}

// ---------------------------------------------------------------------------
// Gather: R9's 2-wide form (best measured). 2 consecutive-m elements per
// thread: float2 plane stores (512 B/wave), int2 idx loads, 2-record MLP.
// ---------------------------------------------------------------------------
__global__ __launch_bounds__(256) void gather_kernel(
    const float* __restrict__ pf,       // (B,N,36)
    const float* __restrict__ centers,  // (B,3,M)
    const int* __restrict__ idx,        // (B,K,M)
    float* __restrict__ out)            // (B,35,K,M)
{
    const int t = blockIdx.x * 256 + threadIdx.x;   // 0..131071
    const int m = (t & (M_CTR / 2 - 1)) * 2;
    const int k = (t >> 11) & (K_NB - 1);
    const int b = t >> 16;

    const int2 nn = *(const int2*)&idx[(b * K_NB + k) * M_CTR + m];
    const float4* __restrict__ s0 =
        (const float4*)(pf + ((size_t)b * N_PTS + nn.x) * 36);
    const float4* __restrict__ s1 =
        (const float4*)(pf + ((size_t)b * N_PTS + nn.y) * 36);

    float4 f0[9], f1[9];
#pragma unroll
    for (int i = 0; i < 9; ++i) { f0[i] = s0[i]; f1[i] = s1[i]; }

    const float2 cx = *(const float2*)&centers[(b * 3 + 0) * M_CTR + m];
    const float2 cy = *(const float2*)&centers[(b * 3 + 1) * M_CTR + m];
    const float2 cz = *(const float2*)&centers[(b * 3 + 2) * M_CTR + m];

    float v0[36], v1[36];
#pragma unroll
    for (int i = 0; i < 9; ++i) {
        v0[4 * i + 0] = f0[i].x; v0[4 * i + 1] = f0[i].y;
        v0[4 * i + 2] = f0[i].z; v0[4 * i + 3] = f0[i].w;
        v1[4 * i + 0] = f1[i].x; v1[4 * i + 1] = f1[i].y;
        v1[4 * i + 2] = f1[i].z; v1[4 * i + 3] = f1[i].w;
    }
    v0[0] -= cx.x; v0[1] -= cy.x; v0[2] -= cz.x;   // single f32 subtract
    v1[0] -= cx.y; v1[1] -= cy.y; v1[2] -= cz.y;

    float* __restrict__ o = out + ((size_t)b * NCH * K_NB + k) * M_CTR + m;
#pragma unroll
    for (int ch = 0; ch < NCH; ++ch)
        *(float2*)&o[(size_t)ch * CH_STRIDE] = make_float2(v0[ch], v1[ch]);
}

extern "C" void kernel_launch(void* const* d_in, const int* in_sizes, int n_in,
                              void* d_out, int out_size, void* d_ws, size_t ws_size,
                              hipStream_t stream) {
    const float* points  = (const float*)d_in[0];
    const float* centers = (const float*)d_in[1];
    const float* feats   = (const float*)d_in[2];
    float* out = (float*)d_out;

    char* ws = (char*)d_ws;
    int*    idx    = (int*)ws;                               // 1 MiB
    float*  pf     = (float*)(ws + (1u << 20));              // 4.5 MiB
    int*    cursor = (int*)(ws + 5716 * 1024);               // 8 KB
    int*    starts = (int*)(ws + 5732 * 1024);               // 8 KB
    float4* binned = (float4*)(ws + 5764 * 1024);            // 512 KB

    prep_kernel<<<B_SZ + B_SZ * (N_PTS / 64), 1024, 0, stream>>>(
        points, feats, starts, cursor, pf);
    scatter_kernel<<<(B_SZ * N_PTS) / 256, 256, 0, stream>>>(
        points, cursor, binned);
    ball_query_kernel<<<(B_SZ * M_CTR) / 4, 256, 0, stream>>>(
        binned, centers, starts, idx);
    gather_kernel<<<(B_SZ * K_NB * M_CTR / 2) / 256, 256, 0, stream>>>(
        pf, centers, idx, out);
}